// Round 7
// baseline (179.529 us; speedup 1.0000x reference)
//
#include <hip/hip_runtime.h>
#include <hip/hip_bf16.h>

#define DIM 256
#define HW  1024  // 32*32

typedef __attribute__((ext_vector_type(8))) short short8;
typedef __attribute__((ext_vector_type(4))) float floatx4;
typedef __attribute__((ext_vector_type(16))) float floatx16;
typedef __attribute__((address_space(1))) const unsigned int g_u32;
typedef __attribute__((address_space(3))) unsigned int l_u32;

// softmax scale folded into Q at conv epilogue: 0.25 * log2(e)
#define QSCALE 0.36067376022224085f

__device__ inline unsigned short f2bf(float f) {
  union { float f; unsigned u; } v;
  v.f = f;
  unsigned u = v.u;
  u += 0x7fffu + ((u >> 16) & 1u);
  return (unsigned short)(u >> 16);
}

__device__ inline unsigned short f2bf_trunc(float f) {  // RTZ: 1 VALU inst
  union { float f; unsigned u; } v;
  v.f = f;
  return (unsigned short)(v.u >> 16);
}

__device__ inline float ldin(const void* p, long i, int isf32) {
  if (isf32) return ((const float*)p)[i];
  union { unsigned u; float f; } v;
  v.u = ((unsigned)((const unsigned short*)p)[i]) << 16;
  return v.f;
}

// ---------------------------------------------------------------------------
// R21 fused prep (R3-proven version, unchanged).
// wF layout (unchanged): [tap][c8(8)][co16(16)][lane(64)][j(8)],
//   co = co16*16 + (lane&15), ci = c8*32 + (lane>>4)*8 + j.
// ---------------------------------------------------------------------------
__device__ inline int detect_inline(const unsigned short* __restrict__ xr,
                                    int* cnt) {
  if (threadIdx.x == 0) *cnt = 0;
  __syncthreads();
  int local = 0;
  for (int i = threadIdx.x; i < 8192; i += 256) {
    unsigned short u = xr[i];
    if ((u & 0x7F80u) == 0x7F80u) local++;
  }
  if (local) atomicAdd(cnt, local);
  __syncthreads();
  return (*cnt > 0) ? 1 : 0;
}

__device__ inline void frag_repack4(const void* __restrict__ w,
                                    unsigned short* __restrict__ wF, int KK,
                                    int slice, float* __restrict__ Wl,
                                    int isf32) {
  const int t = threadIdx.x;
  const int co16 = slice & 15;
  const int c8   = slice >> 4;
  const int RE = 32 * KK;   // elems per co row (contiguous in source)
  const int RS = RE + 1;    // padded LDS row stride (801 max == 1 mod 32)
  for (int g = 0; g < 4; ++g) {       // 4 co rows per pass
    __syncthreads();                  // previous pass's reads done
    for (int rloc = 0; rloc < 4; ++rloc) {
      const long base =
          ((long)((co16 * 16 + (g << 2) + rloc) * 256 + c8 * 32)) * KK;
      for (int i = t; i < RE; i += 256)
        Wl[rloc * RS + i] = ldin(w, base + i, isf32);
    }
    __syncthreads();
    for (int tap = 0; tap < KK; ++tap) {
      unsigned short* dst = wF + ((((tap << 3) + c8) << 4) + co16) * 512;
      if (t < 128) {
        const int colg = t >> 5;          // local co row 0..3
        const int cis  = t & 31;          // ci-sub 0..31
        const int col  = (g << 2) + colg; // co within co16 tile
        const int lane = ((cis >> 3) << 4) | col;
        const int j    = cis & 7;
        dst[lane * 8 + j] = f2bf(Wl[colg * RS + cis * KK + tap]);
      }
    }
  }
}

__global__ __launch_bounds__(256) void prep_kernel(
    const void* __restrict__ x,  const void* __restrict__ w3,
    const void* __restrict__ b3, const void* __restrict__ w5,
    const void* __restrict__ b5, const void* __restrict__ w7,
    const void* __restrict__ b7, const void* __restrict__ wp,
    unsigned short* __restrict__ xbf,
    unsigned short* __restrict__ wF3, unsigned short* __restrict__ wF5,
    unsigned short* __restrict__ wF7, unsigned short* __restrict__ wpF,
    float* __restrict__ bc, int* __restrict__ flag) {
  __shared__ float Wl[4 * 801];  // 12.8 KB
  __shared__ int cnt;
  const int isf32 = detect_inline((const unsigned short*)x, &cnt);
  const int bid = blockIdx.x;
  const int t = threadIdx.x;
  if (bid < 512) {  // xconv: 16 elems/thread, 4 coalesced rounds
#pragma unroll
    for (int r = 0; r < 4; ++r) {
      const int i = (bid * 1024 + r * 256 + t) * 4;
      if (isf32) {
        const float4 v = *(const float4*)((const float*)x + i);
        ushort4 o;
        o.x = f2bf(v.x); o.y = f2bf(v.y); o.z = f2bf(v.z); o.w = f2bf(v.w);
        *(ushort4*)(xbf + i) = o;
      } else {
        *(ushort4*)(xbf + i) =
            *(const ushort4*)((const unsigned short*)x + i);
      }
    }
  } else if (bid < 640) {
    frag_repack4(w7, wF7, 25, bid - 512, Wl, isf32);
  } else if (bid < 768) {
    frag_repack4(w5, wF5, 9, bid - 640, Wl, isf32);
  } else if (bid < 896) {
    frag_repack4(w3, wF3, 1, bid - 768, Wl, isf32);
  } else if (bid < 1024) {
    frag_repack4(wp, wpF, 1, bid - 896, Wl, isf32);
  } else {  // biases (q=b3, v=b5, k=b7) + publish flag
#pragma unroll
    for (int r = 0; r < 3; ++r) {
      const int i = r * 256 + t;
      const void* src = (i < 256) ? b3 : (i < 512) ? b5 : b7;
      bc[i] = ldin(src, i & 255, isf32);
    }
    if (t == 0) *flag = isf32;
  }
}

// ---------------------------------------------------------------------------
// R27 conv (resubmitted; R6 was an infra failure, no measurement): 2-phase B
// staging (T3 minimum recipe inside the proven body). R24/R25/R26 falsified
// LDS-reads / X-latency / bank-conflicts as limiters; remaining candidate is
// the barrier-2 vmcnt(0) drain of all 35 B-DMAs on every block's critical
// path. Split: drain only taps 0-17 at barrier-2; issue taps 18-34 BEFORE
// phase-1 compute (18 k-taps ~2.5Kcy) so their drain at barrier-3 is free.
// Phase-1 = k taps 0..17; phase-2 = k taps 18..24 + all 9 v-taps (re-read
// their a-frags; reads proven non-binding) + q (B-slot 34 lives in half 2).
// MFMA count/layouts/LDS/occupancy unchanged. R26 write remap kept.
// Attention coords (R2/R11-verified): slab=(b<<4)+(co>>4), m=(co&15)*64+(n>>4),
//   d=n&15;  q/k rows: (slab<<14)+((co&15)<<10)+n ;  v (V^T):
//   (slab<<14)+((n&15)<<10)+((co&15)<<6)+(n>>4)
// ---------------------------------------------------------------------------
__global__ __launch_bounds__(256, 2) void convqkv_kernel(
    const unsigned short* __restrict__ xbf,
    const unsigned short* __restrict__ wFq,  // 1 tap
    const unsigned short* __restrict__ wFv,  // 9 taps
    const unsigned short* __restrict__ wFk,  // 25 taps
    const float* __restrict__ bc,            // [3][256] q,v,k
    unsigned short* __restrict__ qOut,
    unsigned short* __restrict__ vOut,
    unsigned short* __restrict__ kOut) {
  constexpr int WC = 36;            // halo cols (32 + 2*2)
  constexpr int CELLS = 12 * WC;    // 12 halo rows = 432 cells
  __shared__ unsigned short Xs[CELLS * 40];  // halo [cell][32ci pad40] 34.6KB
  __shared__ unsigned short Bs[36 * 512];    // B [tap35+1][lane64][8]  36.9KB
  const int t    = threadIdx.x;
  const int bid  = blockIdx.x;
  const int cog0 = bid & 15;
  const int co0  = cog0 << 4;
  const int m0   = (bid >> 4) << 8;    // 256 positions (8 image rows)
  const int b    = m0 >> 10;
  const int n0   = m0 & 1023;
  const int r0   = n0 >> 5;
  const int wv   = t >> 6;
  const int lane = t & 63;
  const int l15  = lane & 15;
  const int quad = lane >> 4;

  floatx4 aq[4] = {}, av[4] = {}, ak[4] = {};

  for (int c8 = 0; c8 < 8; ++c8) {
    uint4 xreg[7];
#pragma unroll
    for (int rr = 0; rr < 7; ++rr) {
      const int id = rr * 256 + t;
      const int grp = id >> 6;                       // 0..27
      const int part = grp & 3;
      const int cell = ((grp >> 2) << 6) + (id & 63);  // 64 consecutive/wave
      const int hr = cell / WC, wc = cell - hr * WC;
      const int xr = r0 + hr - 2, xc = wc - 2;
      const bool ok = (cell < CELLS) && ((unsigned)xr < 32u) &&
                      ((unsigned)xc < 32u);
      const int cr = xr < 0 ? 0 : (xr > 31 ? 31 : xr);
      const int cc = xc < 0 ? 0 : (xc > 31 ? 31 : xc);
      uint4 v = *(const uint4*)&xbf[(((b * 32 + cr) * 32 + cc) << 8) +
                                    (c8 << 5) + (part << 3)];
      if (!ok) v = make_uint4(0, 0, 0, 0);
      xreg[rr] = v;
    }
    __syncthreads();  // barrier1: prev phase-2 done reading Xs/Bs
    // B-DMA half 1: taps 0..17 (k only)
#pragma unroll
    for (int rr = 0; rr < 5; ++rr) {
      const int tap = (rr << 2) + wv;    // 0..19
      if (tap < 18) {
        const unsigned short* src =
            &wFk[((((tap << 3) + c8) << 4) + cog0) * 512];
        __builtin_amdgcn_global_load_lds((g_u32*)(src + (lane << 3)),
                                         (l_u32*)&Bs[tap << 9], 16, 0, 0);
      }
    }
#pragma unroll
    for (int rr = 0; rr < 7; ++rr) {
      const int id = rr * 256 + t;
      const int grp = id >> 6;
      const int cell = ((grp >> 2) << 6) + (id & 63);
      if (cell < CELLS)
        *(uint4*)&Xs[cell * 40 + ((grp & 3) << 3)] = xreg[rr];
    }
    __syncthreads();  // barrier2: Xs + B half 1 visible (drains 18 DMAs)

    // B-DMA half 2 issued NOW; lands under phase-1 compute (~18 k-taps)
#pragma unroll
    for (int rr = 0; rr < 5; ++rr) {
      const int tap = 18 + (rr << 2) + wv;  // 18..37
      if (tap < 35) {
        const unsigned short* src;
        if (tap < 25) {
          src = &wFk[((((tap << 3) + c8) << 4) + cog0) * 512];
        } else if (tap < 34) {
          src = &wFv[(((((tap - 25) << 3) + c8) << 4) + cog0) * 512];
        } else {
          src = &wFq[((c8 << 4) + cog0) * 512];
        }
        __builtin_amdgcn_global_load_lds((g_u32*)(src + (lane << 3)),
                                         (l_u32*)&Bs[tap << 9], 16, 0, 0);
      }
    }

    // ---- phase 1: k taps 0..17 ----
#pragma unroll
    for (int tap = 0; tap < 18; ++tap) {
      const int kh = tap / 5, kw = tap % 5;
      short8 a[4];
#pragma unroll
      for (int rr2 = 0; rr2 < 2; ++rr2) {
#pragma unroll
        for (int ch = 0; ch < 2; ++ch) {
          const unsigned short* xs =
              &Xs[(((wv << 1) + rr2 + kh) * WC + (ch << 4) + l15 + kw) * 40 +
                  (quad << 3)];
          a[(rr2 << 1) + ch] = *(const short8*)xs;
        }
      }
      const short8 kb = *(const short8*)&Bs[(tap << 9) + (lane << 3)];
#pragma unroll
      for (int f = 0; f < 4; ++f)
        ak[f] = __builtin_amdgcn_mfma_f32_16x16x32_bf16(a[f], kb, ak[f],
                                                        0, 0, 0);
    }
    __syncthreads();  // barrier3: B half 2 visible (DMA had phase-1 to land)

    // ---- phase 2: k taps 18..24, then v taps (+q at vt==4) ----
#pragma unroll
    for (int tap = 18; tap < 25; ++tap) {
      const int kh = tap / 5, kw = tap % 5;
      short8 a[4];
#pragma unroll
      for (int rr2 = 0; rr2 < 2; ++rr2) {
#pragma unroll
        for (int ch = 0; ch < 2; ++ch) {
          const unsigned short* xs =
              &Xs[(((wv << 1) + rr2 + kh) * WC + (ch << 4) + l15 + kw) * 40 +
                  (quad << 3)];
          a[(rr2 << 1) + ch] = *(const short8*)xs;
        }
      }
      const short8 kb = *(const short8*)&Bs[(tap << 9) + (lane << 3)];
#pragma unroll
      for (int f = 0; f < 4; ++f)
        ak[f] = __builtin_amdgcn_mfma_f32_16x16x32_bf16(a[f], kb, ak[f],
                                                        0, 0, 0);
    }
#pragma unroll
    for (int vt = 0; vt < 9; ++vt) {
      const int kh = vt / 3 + 1, kw = vt % 3 + 1;
      short8 a[4];
#pragma unroll
      for (int rr2 = 0; rr2 < 2; ++rr2) {
#pragma unroll
        for (int ch = 0; ch < 2; ++ch) {
          const unsigned short* xs =
              &Xs[(((wv << 1) + rr2 + kh) * WC + (ch << 4) + l15 + kw) * 40 +
                  (quad << 3)];
          a[(rr2 << 1) + ch] = *(const short8*)xs;
        }
      }
      const short8 vb = *(const short8*)&Bs[((25 + vt) << 9) + (lane << 3)];
#pragma unroll
      for (int f = 0; f < 4; ++f)
        av[f] = __builtin_amdgcn_mfma_f32_16x16x32_bf16(a[f], vb, av[f],
                                                        0, 0, 0);
      if (vt == 4) {  // tap 12 center: q shares these a-frags
        const short8 qb = *(const short8*)&Bs[(34 << 9) + (lane << 3)];
#pragma unroll
        for (int f = 0; f < 4; ++f)
          aq[f] = __builtin_amdgcn_mfma_f32_16x16x32_bf16(a[f], qb, aq[f],
                                                          0, 0, 0);
      }
    }
  }
#pragma unroll
  for (int rr2 = 0; rr2 < 2; ++rr2) {
#pragma unroll
    for (int ch = 0; ch < 2; ++ch) {
      const int f = (rr2 << 1) + ch;
      const int co = co0 + l15;
      const int slab = (b << 4) + (co >> 4);
      const int clo = co & 15;
      const int nb = n0 + (wv << 6) + (rr2 << 5) + (ch << 4) + (quad << 2);
      {
        const float bj = bc[co];
        floatx4 a = aq[f];
        ushort4 pk4;
        pk4.x = f2bf((a[0] + bj) * QSCALE);
        pk4.y = f2bf((a[1] + bj) * QSCALE);
        pk4.z = f2bf((a[2] + bj) * QSCALE);
        pk4.w = f2bf((a[3] + bj) * QSCALE);
        *(ushort4*)&qOut[(slab << 14) + (clo << 10) + nb] = pk4;
      }
      {
        const float bj = bc[512 + co];
        floatx4 a = ak[f];
        ushort4 pk4;
        pk4.x = f2bf(a[0] + bj); pk4.y = f2bf(a[1] + bj);
        pk4.z = f2bf(a[2] + bj); pk4.w = f2bf(a[3] + bj);
        *(ushort4*)&kOut[(slab << 14) + (clo << 10) + nb] = pk4;
      }
      {
        const float bj = bc[256 + co];
        floatx4 a = av[f];
        const int base = (slab << 14) + (clo << 6);
#pragma unroll
        for (int i = 0; i < 4; ++i) {
          const int n = nb + i;
          vOut[base + ((n & 15) << 10) + (n >> 4)] = f2bf(a[i] + bj);
        }
      }
    }
  }
}

// ---------------------------------------------------------------------------
// R27 attn: exact R3/R24-proven version (best total). Swapped QK^T
// (mfma(kb,qa)): lane holds P[q=l31][k], 4 consecutive k per reg group ->
// packed P-store = 8 v_cvt_pk_bf16_f32 + 4 ds_write_b64 per iter.
// setprio reverted (R26: -6us, m190-regime not m191).
// ---------------------------------------------------------------------------
__global__ __launch_bounds__(256, 4) void attn_mfma_kernel(
    const unsigned short* __restrict__ qg,
    const unsigned short* __restrict__ kg,
    const unsigned short* __restrict__ vg,
    unsigned short* __restrict__ out2) {
  __shared__ __align__(16) unsigned short Pb[4][32][40];  // per-wave P
  const int t    = threadIdx.x;
  const int w    = t >> 6;
  const int lane = t & 63;
  const int slab = blockIdx.x >> 3;
  const int rb   = blockIdx.x & 7;
  const int b = slab >> 4;
  const int h = slab & 15;
  const int l31  = lane & 31;
  const int hl   = lane >> 5;
  const int l15  = lane & 15;
  const int quad = lane >> 4;

  const unsigned short* Kb = kg + (slab << 14);
  const unsigned short* Vb = vg + (slab << 14);

  const int row0 = (rb << 7) + (w << 5);
  const short8 qa =
      *(const short8*)&qg[(slab << 14) + ((row0 + l31) << 4) + (hl << 3)];

  const short onebf = (short)0x3F80;  // bf16 1.0
  const short8 ones = {onebf, onebf, onebf, onebf, onebf, onebf, onebf, onebf};

  floatx4 acco[2] = {}, asum[2] = {};

  for (int kc = 0; kc < 1024; kc += 32) {
    const short8 kb = *(const short8*)&Kb[((kc + l31) << 4) + (hl << 3)];
    floatx16 s = {};
    // swapped: D[m=k][n=q] -> lane holds q=l31, k = 8g + 4hl + j for s[4g+j]
    s = __builtin_amdgcn_mfma_f32_32x32x16_bf16(kb, qa, s, 0, 0, 0);
#pragma unroll
    for (int g = 0; g < 4; ++g) {
      const float e0 = __builtin_amdgcn_exp2f(s[(g << 2) + 0]);
      const float e1 = __builtin_amdgcn_exp2f(s[(g << 2) + 1]);
      const float e2 = __builtin_amdgcn_exp2f(s[(g << 2) + 2]);
      const float e3 = __builtin_amdgcn_exp2f(s[(g << 2) + 3]);
      unsigned lo, hi;
      asm("v_cvt_pk_bf16_f32 %0, %1, %2" : "=v"(lo) : "v"(e0), "v"(e1));
      asm("v_cvt_pk_bf16_f32 %0, %1, %2" : "=v"(hi) : "v"(e2), "v"(e3));
      uint2 pk; pk.x = lo; pk.y = hi;
      *(uint2*)&Pb[w][l31][(g << 3) + (hl << 2)] = pk;  // k=8g+4hl..+3
    }
    const short8 vb = *(const short8*)&Vb[(l15 << 10) + kc + (quad << 3)];
#pragma unroll
    for (int tt = 0; tt < 2; ++tt) {
      const short8 pa = *(const short8*)&Pb[w][(tt << 4) + l15][quad << 3];
      acco[tt] =
          __builtin_amdgcn_mfma_f32_16x16x32_bf16(pa, vb, acco[tt], 0, 0, 0);
      asum[tt] =
          __builtin_amdgcn_mfma_f32_16x16x32_bf16(pa, ones, asum[tt], 0, 0, 0);
    }
  }
#pragma unroll
  for (int tt = 0; tt < 2; ++tt) {
#pragma unroll
    for (int r = 0; r < 4; ++r) {
      const int nloc = (tt << 4) + (quad << 2) + r;
      const float val = acco[tt][r] / asum[tt][r];
      const int n = row0 + nloc;
      out2[(((b << 10) + n) << 8) + (h << 4) + l15] = f2bf(val);
    }
  }
}

// ---------------------------------------------------------------------------
// Final linear (R3-proven LDS-staged version), MFMA bf16, with one-chunk-
// ahead B register prefetch.
// ---------------------------------------------------------------------------
__global__ __launch_bounds__(256) void linear_mfma_kernel(
    const unsigned short* __restrict__ inp,  // bf16 [8192][256]
    const unsigned short* __restrict__ wpF,  // fragment order
    void* __restrict__ out, const int* __restrict__ flag) {
  __shared__ unsigned short As[64 * 40];
  const int isf32 = *flag;
  const int t   = threadIdx.x;
  const int m0  = blockIdx.x << 6;
  const int co0 = blockIdx.y << 6;
  const int wv   = t >> 6;
  const int lane = t & 63;
  const int wm = (wv & 1) << 5;
  const int wn = (wv >> 1) << 5;
  const int l15  = lane & 15;
  const int quad = lane >> 4;
  const int cogb = (co0 >> 4) + (wn >> 4);
  const int rowS = t >> 2;
  const int partS = t & 3;

  floatx4 acc[2][2] = {};

  short8 cb0, cb1;
  {
    const unsigned short* wptr = &wpF[(cogb << 9) + (lane << 3)];
    cb0 = *(const short8*)wptr;
    cb1 = *(const short8*)(wptr + 512);
  }
  for (int c8 = 0; c8 < 8; ++c8) {
    const uint4 v = *(const uint4*)&inp[((m0 + rowS) << 8) + (c8 << 5) +
                                        (partS << 3)];
    short8 nb0 = {}, nb1 = {};
    if (c8 + 1 < 8) {
      const unsigned short* wptr =
          &wpF[((((c8 + 1) << 4) + cogb) << 9) + (lane << 3)];
      nb0 = *(const short8*)wptr;
      nb1 = *(const short8*)(wptr + 512);
    }
    __syncthreads();
    *(uint4*)&As[rowS * 40 + (partS << 3)] = v;
    __syncthreads();
    const unsigned short* xs = &As[(wm + l15) * 40 + (quad << 3)];
    const short8 afr0 = *(const short8*)xs;
    const short8 afr1 = *(const short8*)(xs + 16 * 40);
    acc[0][0] = __builtin_amdgcn_mfma_f32_16x16x32_bf16(afr0, cb0,
                                                        acc[0][0], 0, 0, 0);
    acc[0][1] = __builtin_amdgcn_mfma_f32_16x16x32_bf16(afr0, cb1,
                                                        acc[0][1], 0, 0, 0);
    acc[1][0] = __builtin_amdgcn_mfma_f32_16x16x32_bf16(afr1, cb0,
                                                        acc[1][0], 0, 0, 0);
    acc[1][1] = __builtin_amdgcn_mfma_f32_16x16x32_bf16(afr1, cb1,
                                                        acc[1][1], 0, 0, 0);
    cb0 = nb0; cb1 = nb1;
  }
#pragma unroll
  for (int mi = 0; mi < 2; ++mi) {
#pragma unroll
    for (int ni = 0; ni < 2; ++ni) {
      const int co = co0 + wn + (ni << 4) + l15;
      const int mb = m0 + wm + (mi << 4) + (quad << 2);
      floatx4 a = acc[mi][ni];
      if (!isf32) {
        unsigned short* o16 = (unsigned short*)out;
#pragma unroll
        for (int r = 0; r < 4; ++r) o16[(mb + r) * 256 + co] = f2bf(a[r]);
      } else {
        float* o32 = (float*)out;
#pragma unroll
        for (int r = 0; r < 4; ++r) o32[(mb + r) * 256 + co] = a[r];
      }
    }
  }
}

// ---------------------------------------------------------------------------
extern "C" void kernel_launch(void* const* d_in, const int* in_sizes, int n_in,
                              void* d_out, int out_size, void* d_ws,
                              size_t ws_size, hipStream_t stream) {
  const void* x  = d_in[0];
  const void* w3 = d_in[1];
  const void* b3 = d_in[2];
  const void* w5 = d_in[3];
  const void* b5 = d_in[4];
  const void* w7 = d_in[5];
  const void* b7 = d_in[6];
  const void* wp = d_in[7];

  char* p = (char*)d_ws;
  int* flag = (int*)p;                       p += 256;
  unsigned short* xbf = (unsigned short*)p;  p += 4u * 1024 * 1024;
  unsigned short* wF3 = (unsigned short*)p;  p += 131072;
  unsigned short* wF5 = (unsigned short*)p;  p += 1179648;
  unsigned short* wF7 = (unsigned short*)p;  p += 3276800;
  unsigned short* wpF = (unsigned short*)p;  p += 131072;
  float* bc = (float*)p;                     p += 4096;     // [3][256]
  unsigned short* qc  = (unsigned short*)p;  p += 4194304;  // bf16 QK rows
  unsigned short* kT  = (unsigned short*)p;  p += 4194304;  // bf16 QK rows
  unsigned short* vT  = (unsigned short*)p;  p += 4194304;  // bf16 V^T
  unsigned short* o2b = (unsigned short*)p;  p += 4194304;  // bf16 [8192][256]

  prep_kernel<<<1025, 256, 0, stream>>>(x, w3, b3, w5, b5, w7, b7, wp, xbf,
                                        wF3, wF5, wF7, wpF, bc, flag);

  convqkv_kernel<<<512, 256, 0, stream>>>(xbf, wF3, wF5, wF7, bc, qc, vT, kT);

  attn_mfma_kernel<<<1024, 256, 0, stream>>>(qc, kT, vT, o2b);

  dim3 lg(128, 4);
  linear_mfma_kernel<<<lg, 256, 0, stream>>>(o2b, wpF, d_out, flag);
}

// Round 8
// 175.012 us; speedup vs baseline: 1.0258x; 1.0258x over previous
//
#include <hip/hip_runtime.h>
#include <hip/hip_bf16.h>

#define DIM 256
#define HW  1024  // 32*32

typedef __attribute__((ext_vector_type(8))) short short8;
typedef __attribute__((ext_vector_type(4))) float floatx4;
typedef __attribute__((ext_vector_type(16))) float floatx16;
typedef __attribute__((address_space(1))) const unsigned int g_u32;
typedef __attribute__((address_space(3))) unsigned int l_u32;

// softmax scale folded into Q at conv epilogue: 0.25 * log2(e)
#define QSCALE 0.36067376022224085f

__device__ inline unsigned short f2bf(float f) {
  union { float f; unsigned u; } v;
  v.f = f;
  unsigned u = v.u;
  u += 0x7fffu + ((u >> 16) & 1u);
  return (unsigned short)(u >> 16);
}

__device__ inline unsigned short f2bf_trunc(float f) {  // RTZ: 1 VALU inst
  union { float f; unsigned u; } v;
  v.f = f;
  return (unsigned short)(v.u >> 16);
}

__device__ inline float ldin(const void* p, long i, int isf32) {
  if (isf32) return ((const float*)p)[i];
  union { unsigned u; float f; } v;
  v.u = ((unsigned)((const unsigned short*)p)[i]) << 16;
  return v.f;
}

// ---------------------------------------------------------------------------
// R21 fused prep (R3-proven version, verbatim).
// wF layout: [tap][c8(8)][co16(16)][lane(64)][j(8)],
//   co = co16*16 + (lane&15), ci = c8*32 + (lane>>4)*8 + j.
// ---------------------------------------------------------------------------
__device__ inline int detect_inline(const unsigned short* __restrict__ xr,
                                    int* cnt) {
  if (threadIdx.x == 0) *cnt = 0;
  __syncthreads();
  int local = 0;
  for (int i = threadIdx.x; i < 8192; i += 256) {
    unsigned short u = xr[i];
    if ((u & 0x7F80u) == 0x7F80u) local++;
  }
  if (local) atomicAdd(cnt, local);
  __syncthreads();
  return (*cnt > 0) ? 1 : 0;
}

__device__ inline void frag_repack4(const void* __restrict__ w,
                                    unsigned short* __restrict__ wF, int KK,
                                    int slice, float* __restrict__ Wl,
                                    int isf32) {
  const int t = threadIdx.x;
  const int co16 = slice & 15;
  const int c8   = slice >> 4;
  const int RE = 32 * KK;   // elems per co row (contiguous in source)
  const int RS = RE + 1;    // padded LDS row stride (801 max == 1 mod 32)
  for (int g = 0; g < 4; ++g) {       // 4 co rows per pass
    __syncthreads();                  // previous pass's reads done
    for (int rloc = 0; rloc < 4; ++rloc) {
      const long base =
          ((long)((co16 * 16 + (g << 2) + rloc) * 256 + c8 * 32)) * KK;
      for (int i = t; i < RE; i += 256)
        Wl[rloc * RS + i] = ldin(w, base + i, isf32);
    }
    __syncthreads();
    for (int tap = 0; tap < KK; ++tap) {
      unsigned short* dst = wF + ((((tap << 3) + c8) << 4) + co16) * 512;
      if (t < 128) {
        const int colg = t >> 5;          // local co row 0..3
        const int cis  = t & 31;          // ci-sub 0..31
        const int col  = (g << 2) + colg; // co within co16 tile
        const int lane = ((cis >> 3) << 4) | col;
        const int j    = cis & 7;
        dst[lane * 8 + j] = f2bf(Wl[colg * RS + cis * KK + tap]);
      }
    }
  }
}

__global__ __launch_bounds__(256) void prep_kernel(
    const void* __restrict__ x,  const void* __restrict__ w3,
    const void* __restrict__ b3, const void* __restrict__ w5,
    const void* __restrict__ b5, const void* __restrict__ w7,
    const void* __restrict__ b7, const void* __restrict__ wp,
    unsigned short* __restrict__ xbf,
    unsigned short* __restrict__ wF3, unsigned short* __restrict__ wF5,
    unsigned short* __restrict__ wF7, unsigned short* __restrict__ wpF,
    float* __restrict__ bc, int* __restrict__ flag) {
  __shared__ float Wl[4 * 801];  // 12.8 KB
  __shared__ int cnt;
  const int isf32 = detect_inline((const unsigned short*)x, &cnt);
  const int bid = blockIdx.x;
  const int t = threadIdx.x;
  if (bid < 512) {  // xconv: 16 elems/thread, 4 coalesced rounds
#pragma unroll
    for (int r = 0; r < 4; ++r) {
      const int i = (bid * 1024 + r * 256 + t) * 4;
      if (isf32) {
        const float4 v = *(const float4*)((const float*)x + i);
        ushort4 o;
        o.x = f2bf(v.x); o.y = f2bf(v.y); o.z = f2bf(v.z); o.w = f2bf(v.w);
        *(ushort4*)(xbf + i) = o;
      } else {
        *(ushort4*)(xbf + i) =
            *(const ushort4*)((const unsigned short*)x + i);
      }
    }
  } else if (bid < 640) {
    frag_repack4(w7, wF7, 25, bid - 512, Wl, isf32);
  } else if (bid < 768) {
    frag_repack4(w5, wF5, 9, bid - 640, Wl, isf32);
  } else if (bid < 896) {
    frag_repack4(w3, wF3, 1, bid - 768, Wl, isf32);
  } else if (bid < 1024) {
    frag_repack4(wp, wpF, 1, bid - 896, Wl, isf32);
  } else {  // biases (q=b3, v=b5, k=b7) + publish flag
#pragma unroll
    for (int r = 0; r < 3; ++r) {
      const int i = r * 256 + t;
      const void* src = (i < 256) ? b3 : (i < 512) ? b5 : b7;
      bc[i] = ldin(src, i & 255, isf32);
    }
    if (t == 0) *flag = isf32;
  }
}

// ---------------------------------------------------------------------------
// R28 conv = R3/R24-verbatim (best-total composition, 170.2us run). Conv is
// declared at its 2-barrier structural ceiling: R24 (-40% LDS reads), R25
// (X-latency hidden), R26 (-18% write conflicts), R27 (2-phase DMA split)
// were all flat or negative. kw-outer X-fragment register reuse; 2 blocks/CU.
// Attention coords (R2/R11-verified): slab=(b<<4)+(co>>4), m=(co&15)*64+(n>>4),
//   d=n&15;  q/k rows: (slab<<14)+((co&15)<<10)+n ;  v (V^T):
//   (slab<<14)+((n&15)<<10)+((co&15)<<6)+(n>>4)
// ---------------------------------------------------------------------------
__global__ __launch_bounds__(256, 2) void convqkv_kernel(
    const unsigned short* __restrict__ xbf,
    const unsigned short* __restrict__ wFq,  // 1 tap
    const unsigned short* __restrict__ wFv,  // 9 taps
    const unsigned short* __restrict__ wFk,  // 25 taps
    const float* __restrict__ bc,            // [3][256] q,v,k
    unsigned short* __restrict__ qOut,
    unsigned short* __restrict__ vOut,
    unsigned short* __restrict__ kOut) {
  constexpr int WC = 36;            // halo cols (32 + 2*2)
  constexpr int CELLS = 12 * WC;    // 12 halo rows = 432 cells
  constexpr int LOADS = CELLS * 4;  // 1728 halo dwordx4 loads
  __shared__ unsigned short Xs[CELLS * 40];  // halo [cell][32ci pad40] 34.6KB
  __shared__ unsigned short Bs[36 * 512];    // B [tap35+1][lane64][8]  36.9KB
  const int t    = threadIdx.x;
  const int bid  = blockIdx.x;
  const int cog0 = bid & 15;
  const int co0  = cog0 << 4;
  const int m0   = (bid >> 4) << 8;    // 256 positions (8 image rows)
  const int b    = m0 >> 10;
  const int n0   = m0 & 1023;
  const int r0   = n0 >> 5;
  const int wv   = t >> 6;
  const int lane = t & 63;
  const int l15  = lane & 15;
  const int quad = lane >> 4;

  floatx4 aq[4] = {}, av[4] = {}, ak[4] = {};

  for (int c8 = 0; c8 < 8; ++c8) {
    uint4 xreg[7];
#pragma unroll
    for (int rr = 0; rr < 7; ++rr) {
      const int id = rr * 256 + t;
      const int cell = id >> 2, part = id & 3;
      const int hr = cell / WC, wc = cell - hr * WC;
      const int xr = r0 + hr - 2, xc = wc - 2;
      const bool ok = (id < LOADS) && ((unsigned)xr < 32u) &&
                      ((unsigned)xc < 32u);
      const int cr = xr < 0 ? 0 : (xr > 31 ? 31 : xr);
      const int cc = xc < 0 ? 0 : (xc > 31 ? 31 : xc);
      uint4 v = *(const uint4*)&xbf[(((b * 32 + cr) * 32 + cc) << 8) +
                                    (c8 << 5) + (part << 3)];
      if (!ok) v = make_uint4(0, 0, 0, 0);
      xreg[rr] = v;
    }
    __syncthreads();
#pragma unroll
    for (int rr = 0; rr < 9; ++rr) {
      const int tap = (rr << 2) + wv;
      if (tap < 35) {
        const unsigned short* src;
        if (tap < 25) {
          src = &wFk[((((tap << 3) + c8) << 4) + cog0) * 512];
        } else if (tap < 34) {
          src = &wFv[(((((tap - 25) << 3) + c8) << 4) + cog0) * 512];
        } else {
          src = &wFq[((c8 << 4) + cog0) * 512];
        }
        __builtin_amdgcn_global_load_lds((g_u32*)(src + (lane << 3)),
                                         (l_u32*)&Bs[tap << 9], 16, 0, 0);
      }
    }
#pragma unroll
    for (int rr = 0; rr < 7; ++rr) {
      const int id = rr * 256 + t;
      if (id < LOADS)
        *(uint4*)&Xs[(id >> 2) * 40 + ((id & 3) << 3)] = xreg[rr];
    }
    __syncthreads();

#pragma unroll
    for (int kw = 0; kw < 5; ++kw) {
      // 12 distinct X frags for this kw: rows (wv*2 + 0..5), ch 0..1.
      short8 a[6][2];
#pragma unroll
      for (int ri = 0; ri < 6; ++ri) {
#pragma unroll
        for (int ch = 0; ch < 2; ++ch) {
          const unsigned short* xs =
              &Xs[(((wv << 1) + ri) * WC + (ch << 4) + l15 + kw) * 40 +
                  (quad << 3)];
          a[ri][ch] = *(const short8*)xs;
        }
      }
#pragma unroll
      for (int kh = 0; kh < 5; ++kh) {
        const int tap = kh * 5 + kw;
        const short8 kb = *(const short8*)&Bs[(tap << 9) + (lane << 3)];
#pragma unroll
        for (int rr2 = 0; rr2 < 2; ++rr2) {
#pragma unroll
          for (int ch = 0; ch < 2; ++ch) {
            const int f = (rr2 << 1) + ch;
            ak[f] = __builtin_amdgcn_mfma_f32_16x16x32_bf16(
                a[rr2 + kh][ch], kb, ak[f], 0, 0, 0);
          }
        }
        if (kh >= 1 && kh <= 3 && kw >= 1 && kw <= 3) {
          const int vt = (kh - 1) * 3 + (kw - 1);
          const short8 vb =
              *(const short8*)&Bs[((25 + vt) << 9) + (lane << 3)];
#pragma unroll
          for (int rr2 = 0; rr2 < 2; ++rr2) {
#pragma unroll
            for (int ch = 0; ch < 2; ++ch) {
              const int f = (rr2 << 1) + ch;
              av[f] = __builtin_amdgcn_mfma_f32_16x16x32_bf16(
                  a[rr2 + kh][ch], vb, av[f], 0, 0, 0);
            }
          }
        }
        if (tap == 12) {
          const short8 qb = *(const short8*)&Bs[(34 << 9) + (lane << 3)];
#pragma unroll
          for (int rr2 = 0; rr2 < 2; ++rr2) {
#pragma unroll
            for (int ch = 0; ch < 2; ++ch) {
              const int f = (rr2 << 1) + ch;
              aq[f] = __builtin_amdgcn_mfma_f32_16x16x32_bf16(
                  a[rr2 + kh][ch], qb, aq[f], 0, 0, 0);
            }
          }
        }
      }
    }
  }
#pragma unroll
  for (int rr2 = 0; rr2 < 2; ++rr2) {
#pragma unroll
    for (int ch = 0; ch < 2; ++ch) {
      const int f = (rr2 << 1) + ch;
      const int co = co0 + l15;
      const int slab = (b << 4) + (co >> 4);
      const int clo = co & 15;
      const int nb = n0 + (wv << 6) + (rr2 << 5) + (ch << 4) + (quad << 2);
      {
        const float bj = bc[co];
        floatx4 a = aq[f];
        ushort4 pk4;
        pk4.x = f2bf((a[0] + bj) * QSCALE);
        pk4.y = f2bf((a[1] + bj) * QSCALE);
        pk4.z = f2bf((a[2] + bj) * QSCALE);
        pk4.w = f2bf((a[3] + bj) * QSCALE);
        *(ushort4*)&qOut[(slab << 14) + (clo << 10) + nb] = pk4;
      }
      {
        const float bj = bc[512 + co];
        floatx4 a = ak[f];
        ushort4 pk4;
        pk4.x = f2bf(a[0] + bj); pk4.y = f2bf(a[1] + bj);
        pk4.z = f2bf(a[2] + bj); pk4.w = f2bf(a[3] + bj);
        *(ushort4*)&kOut[(slab << 14) + (clo << 10) + nb] = pk4;
      }
      {
        const float bj = bc[256 + co];
        floatx4 a = av[f];
        const int base = (slab << 14) + (clo << 6);
#pragma unroll
        for (int i = 0; i < 4; ++i) {
          const int n = nb + i;
          vOut[base + ((n & 15) << 10) + (n >> 4)] = f2bf(a[i] + bj);
        }
      }
    }
  }
}

// ---------------------------------------------------------------------------
// R28 attn: R3's swapped-QK^T + packed P-store (the -8us proven win), plus
// ONE isolated change: next-iter K/V register prefetch at loop top. Every
// iteration previously began with a dependent ~200cy L2 K-load feeding the
// QK MFMA -- 32 serial chains/wave at only 4 waves/SIMD TLP. The prefetch
// overlaps iter i+1's loads with iter i's full body. (R25 bundled this with
// 3 other changes at net +7us; conv was counter-flat, attribution unknown --
// this round isolates it.) Wrap-indexing avoids a tail branch.
// ---------------------------------------------------------------------------
__global__ __launch_bounds__(256, 4) void attn_mfma_kernel(
    const unsigned short* __restrict__ qg,
    const unsigned short* __restrict__ kg,
    const unsigned short* __restrict__ vg,
    unsigned short* __restrict__ out2) {
  __shared__ __align__(16) unsigned short Pb[4][32][40];  // per-wave P
  const int t    = threadIdx.x;
  const int w    = t >> 6;
  const int lane = t & 63;
  const int slab = blockIdx.x >> 3;
  const int rb   = blockIdx.x & 7;
  const int b = slab >> 4;
  const int h = slab & 15;
  const int l31  = lane & 31;
  const int hl   = lane >> 5;
  const int l15  = lane & 15;
  const int quad = lane >> 4;

  const unsigned short* Kb = kg + (slab << 14);
  const unsigned short* Vb = vg + (slab << 14);

  const int row0 = (rb << 7) + (w << 5);
  const short8 qa =
      *(const short8*)&qg[(slab << 14) + ((row0 + l31) << 4) + (hl << 3)];

  const short onebf = (short)0x3F80;  // bf16 1.0
  const short8 ones = {onebf, onebf, onebf, onebf, onebf, onebf, onebf, onebf};

  floatx4 acco[2] = {}, asum[2] = {};

  short8 kb = *(const short8*)&Kb[(l31 << 4) + (hl << 3)];
  short8 vb = *(const short8*)&Vb[(l15 << 10) + (quad << 3)];

  for (int kc = 0; kc < 1024; kc += 32) {
    const int kn = (kc + 32) & 1023;  // wraps to 0 on last iter (unused)
    const short8 kb_n =
        *(const short8*)&Kb[((kn + l31) << 4) + (hl << 3)];
    const short8 vb_n =
        *(const short8*)&Vb[(l15 << 10) + kn + (quad << 3)];
    floatx16 s = {};
    // swapped: D[m=k][n=q] -> lane holds q=l31, k = 8g + 4hl + j for s[4g+j]
    s = __builtin_amdgcn_mfma_f32_32x32x16_bf16(kb, qa, s, 0, 0, 0);
#pragma unroll
    for (int g = 0; g < 4; ++g) {
      const float e0 = __builtin_amdgcn_exp2f(s[(g << 2) + 0]);
      const float e1 = __builtin_amdgcn_exp2f(s[(g << 2) + 1]);
      const float e2 = __builtin_amdgcn_exp2f(s[(g << 2) + 2]);
      const float e3 = __builtin_amdgcn_exp2f(s[(g << 2) + 3]);
      unsigned lo, hi;
      asm("v_cvt_pk_bf16_f32 %0, %1, %2" : "=v"(lo) : "v"(e0), "v"(e1));
      asm("v_cvt_pk_bf16_f32 %0, %1, %2" : "=v"(hi) : "v"(e2), "v"(e3));
      uint2 pk; pk.x = lo; pk.y = hi;
      *(uint2*)&Pb[w][l31][(g << 3) + (hl << 2)] = pk;  // k=8g+4hl..+3
    }
#pragma unroll
    for (int tt = 0; tt < 2; ++tt) {
      const short8 pa = *(const short8*)&Pb[w][(tt << 4) + l15][quad << 3];
      acco[tt] =
          __builtin_amdgcn_mfma_f32_16x16x32_bf16(pa, vb, acco[tt], 0, 0, 0);
      asum[tt] =
          __builtin_amdgcn_mfma_f32_16x16x32_bf16(pa, ones, asum[tt], 0, 0, 0);
    }
    kb = kb_n; vb = vb_n;
  }
#pragma unroll
  for (int tt = 0; tt < 2; ++tt) {
#pragma unroll
    for (int r = 0; r < 4; ++r) {
      const int nloc = (tt << 4) + (quad << 2) + r;
      const float val = acco[tt][r] / asum[tt][r];
      const int n = row0 + nloc;
      out2[(((b << 10) + n) << 8) + (h << 4) + l15] = f2bf(val);
    }
  }
}

// ---------------------------------------------------------------------------
// Final linear (R3-proven LDS-staged version, verbatim), MFMA bf16, with
// one-chunk-ahead B register prefetch.
// ---------------------------------------------------------------------------
__global__ __launch_bounds__(256) void linear_mfma_kernel(
    const unsigned short* __restrict__ inp,  // bf16 [8192][256]
    const unsigned short* __restrict__ wpF,  // fragment order
    void* __restrict__ out, const int* __restrict__ flag) {
  __shared__ unsigned short As[64 * 40];
  const int isf32 = *flag;
  const int t   = threadIdx.x;
  const int m0  = blockIdx.x << 6;
  const int co0 = blockIdx.y << 6;
  const int wv   = t >> 6;
  const int lane = t & 63;
  const int wm = (wv & 1) << 5;
  const int wn = (wv >> 1) << 5;
  const int l15  = lane & 15;
  const int quad = lane >> 4;
  const int cogb = (co0 >> 4) + (wn >> 4);
  const int rowS = t >> 2;
  const int partS = t & 3;

  floatx4 acc[2][2] = {};

  short8 cb0, cb1;
  {
    const unsigned short* wptr = &wpF[(cogb << 9) + (lane << 3)];
    cb0 = *(const short8*)wptr;
    cb1 = *(const short8*)(wptr + 512);
  }
  for (int c8 = 0; c8 < 8; ++c8) {
    const uint4 v = *(const uint4*)&inp[((m0 + rowS) << 8) + (c8 << 5) +
                                        (partS << 3)];
    short8 nb0 = {}, nb1 = {};
    if (c8 + 1 < 8) {
      const unsigned short* wptr =
          &wpF[((((c8 + 1) << 4) + cogb) << 9) + (lane << 3)];
      nb0 = *(const short8*)wptr;
      nb1 = *(const short8*)(wptr + 512);
    }
    __syncthreads();
    *(uint4*)&As[rowS * 40 + (partS << 3)] = v;
    __syncthreads();
    const unsigned short* xs = &As[(wm + l15) * 40 + (quad << 3)];
    const short8 afr0 = *(const short8*)xs;
    const short8 afr1 = *(const short8*)(xs + 16 * 40);
    acc[0][0] = __builtin_amdgcn_mfma_f32_16x16x32_bf16(afr0, cb0,
                                                        acc[0][0], 0, 0, 0);
    acc[0][1] = __builtin_amdgcn_mfma_f32_16x16x32_bf16(afr0, cb1,
                                                        acc[0][1], 0, 0, 0);
    acc[1][0] = __builtin_amdgcn_mfma_f32_16x16x32_bf16(afr1, cb0,
                                                        acc[1][0], 0, 0, 0);
    acc[1][1] = __builtin_amdgcn_mfma_f32_16x16x32_bf16(afr1, cb1,
                                                        acc[1][1], 0, 0, 0);
    cb0 = nb0; cb1 = nb1;
  }
#pragma unroll
  for (int mi = 0; mi < 2; ++mi) {
#pragma unroll
    for (int ni = 0; ni < 2; ++ni) {
      const int co = co0 + wn + (ni << 4) + l15;
      const int mb = m0 + wm + (mi << 4) + (quad << 2);
      floatx4 a = acc[mi][ni];
      if (!isf32) {
        unsigned short* o16 = (unsigned short*)out;
#pragma unroll
        for (int r = 0; r < 4; ++r) o16[(mb + r) * 256 + co] = f2bf(a[r]);
      } else {
        float* o32 = (float*)out;
#pragma unroll
        for (int r = 0; r < 4; ++r) o32[(mb + r) * 256 + co] = a[r];
      }
    }
  }
}

// ---------------------------------------------------------------------------
extern "C" void kernel_launch(void* const* d_in, const int* in_sizes, int n_in,
                              void* d_out, int out_size, void* d_ws,
                              size_t ws_size, hipStream_t stream) {
  const void* x  = d_in[0];
  const void* w3 = d_in[1];
  const void* b3 = d_in[2];
  const void* w5 = d_in[3];
  const void* b5 = d_in[4];
  const void* w7 = d_in[5];
  const void* b7 = d_in[6];
  const void* wp = d_in[7];

  char* p = (char*)d_ws;
  int* flag = (int*)p;                       p += 256;
  unsigned short* xbf = (unsigned short*)p;  p += 4u * 1024 * 1024;
  unsigned short* wF3 = (unsigned short*)p;  p += 131072;
  unsigned short* wF5 = (unsigned short*)p;  p += 1179648;
  unsigned short* wF7 = (unsigned short*)p;  p += 3276800;
  unsigned short* wpF = (unsigned short*)p;  p += 131072;
  float* bc = (float*)p;                     p += 4096;     // [3][256]
  unsigned short* qc  = (unsigned short*)p;  p += 4194304;  // bf16 QK rows
  unsigned short* kT  = (unsigned short*)p;  p += 4194304;  // bf16 QK rows
  unsigned short* vT  = (unsigned short*)p;  p += 4194304;  // bf16 V^T
  unsigned short* o2b = (unsigned short*)p;  p += 4194304;  // bf16 [8192][256]

  prep_kernel<<<1025, 256, 0, stream>>>(x, w3, b3, w5, b5, w7, b7, wp, xbf,
                                        wF3, wF5, wF7, wpF, bc, flag);

  convqkv_kernel<<<512, 256, 0, stream>>>(xbf, wF3, wF5, wF7, bc, qc, vT, kT);

  attn_mfma_kernel<<<1024, 256, 0, stream>>>(qc, kT, vT, o2b);

  dim3 lg(128, 4);
  linear_mfma_kernel<<<lg, 256, 0, stream>>>(o2b, wpF, d_out, flag);
}

// Round 9
// 171.235 us; speedup vs baseline: 1.0484x; 1.0221x over previous
//
#include <hip/hip_runtime.h>
#include <hip/hip_bf16.h>

#define DIM 256
#define HW  1024  // 32*32

typedef __attribute__((ext_vector_type(8))) short short8;
typedef __attribute__((ext_vector_type(4))) float floatx4;
typedef __attribute__((ext_vector_type(16))) float floatx16;
typedef __attribute__((address_space(1))) const unsigned int g_u32;
typedef __attribute__((address_space(3))) unsigned int l_u32;

// softmax scale folded into Q at conv epilogue: 0.25 * log2(e)
#define QSCALE 0.36067376022224085f

__device__ inline unsigned short f2bf(float f) {
  union { float f; unsigned u; } v;
  v.f = f;
  unsigned u = v.u;
  u += 0x7fffu + ((u >> 16) & 1u);
  return (unsigned short)(u >> 16);
}

__device__ inline unsigned short f2bf_trunc(float f) {  // RTZ: 1 VALU inst
  union { float f; unsigned u; } v;
  v.f = f;
  return (unsigned short)(v.u >> 16);
}

__device__ inline float ldin(const void* p, long i, int isf32) {
  if (isf32) return ((const float*)p)[i];
  union { unsigned u; float f; } v;
  v.u = ((unsigned)((const unsigned short*)p)[i]) << 16;
  return v.f;
}

// ---------------------------------------------------------------------------
// R21 fused prep (R3-proven version, verbatim).
// wF layout: [tap][c8(8)][co16(16)][lane(64)][j(8)],
//   co = co16*16 + (lane&15), ci = c8*32 + (lane>>4)*8 + j.
// ---------------------------------------------------------------------------
__device__ inline int detect_inline(const unsigned short* __restrict__ xr,
                                    int* cnt) {
  if (threadIdx.x == 0) *cnt = 0;
  __syncthreads();
  int local = 0;
  for (int i = threadIdx.x; i < 8192; i += 256) {
    unsigned short u = xr[i];
    if ((u & 0x7F80u) == 0x7F80u) local++;
  }
  if (local) atomicAdd(cnt, local);
  __syncthreads();
  return (*cnt > 0) ? 1 : 0;
}

__device__ inline void frag_repack4(const void* __restrict__ w,
                                    unsigned short* __restrict__ wF, int KK,
                                    int slice, float* __restrict__ Wl,
                                    int isf32) {
  const int t = threadIdx.x;
  const int co16 = slice & 15;
  const int c8   = slice >> 4;
  const int RE = 32 * KK;   // elems per co row (contiguous in source)
  const int RS = RE + 1;    // padded LDS row stride (801 max == 1 mod 32)
  for (int g = 0; g < 4; ++g) {       // 4 co rows per pass
    __syncthreads();                  // previous pass's reads done
    for (int rloc = 0; rloc < 4; ++rloc) {
      const long base =
          ((long)((co16 * 16 + (g << 2) + rloc) * 256 + c8 * 32)) * KK;
      for (int i = t; i < RE; i += 256)
        Wl[rloc * RS + i] = ldin(w, base + i, isf32);
    }
    __syncthreads();
    for (int tap = 0; tap < KK; ++tap) {
      unsigned short* dst = wF + ((((tap << 3) + c8) << 4) + co16) * 512;
      if (t < 128) {
        const int colg = t >> 5;          // local co row 0..3
        const int cis  = t & 31;          // ci-sub 0..31
        const int col  = (g << 2) + colg; // co within co16 tile
        const int lane = ((cis >> 3) << 4) | col;
        const int j    = cis & 7;
        dst[lane * 8 + j] = f2bf(Wl[colg * RS + cis * KK + tap]);
      }
    }
  }
}

__global__ __launch_bounds__(256) void prep_kernel(
    const void* __restrict__ x,  const void* __restrict__ w3,
    const void* __restrict__ b3, const void* __restrict__ w5,
    const void* __restrict__ b5, const void* __restrict__ w7,
    const void* __restrict__ b7, const void* __restrict__ wp,
    unsigned short* __restrict__ xbf,
    unsigned short* __restrict__ wF3, unsigned short* __restrict__ wF5,
    unsigned short* __restrict__ wF7, unsigned short* __restrict__ wpF,
    float* __restrict__ bc, int* __restrict__ flag) {
  __shared__ float Wl[4 * 801];  // 12.8 KB
  __shared__ int cnt;
  const int isf32 = detect_inline((const unsigned short*)x, &cnt);
  const int bid = blockIdx.x;
  const int t = threadIdx.x;
  if (bid < 512) {  // xconv: 16 elems/thread, 4 coalesced rounds
#pragma unroll
    for (int r = 0; r < 4; ++r) {
      const int i = (bid * 1024 + r * 256 + t) * 4;
      if (isf32) {
        const float4 v = *(const float4*)((const float*)x + i);
        ushort4 o;
        o.x = f2bf(v.x); o.y = f2bf(v.y); o.z = f2bf(v.z); o.w = f2bf(v.w);
        *(ushort4*)(xbf + i) = o;
      } else {
        *(ushort4*)(xbf + i) =
            *(const ushort4*)((const unsigned short*)x + i);
      }
    }
  } else if (bid < 640) {
    frag_repack4(w7, wF7, 25, bid - 512, Wl, isf32);
  } else if (bid < 768) {
    frag_repack4(w5, wF5, 9, bid - 640, Wl, isf32);
  } else if (bid < 896) {
    frag_repack4(w3, wF3, 1, bid - 768, Wl, isf32);
  } else if (bid < 1024) {
    frag_repack4(wp, wpF, 1, bid - 896, Wl, isf32);
  } else {  // biases (q=b3, v=b5, k=b7) + publish flag
#pragma unroll
    for (int r = 0; r < 3; ++r) {
      const int i = r * 256 + t;
      const void* src = (i < 256) ? b3 : (i < 512) ? b5 : b7;
      bc[i] = ldin(src, i & 255, isf32);
    }
    if (t == 0) *flag = isf32;
  }
}

// ---------------------------------------------------------------------------
// R29 conv = R3/R24-verbatim body + XCD-aware block swizzle (T1, the one
// untried zero-risk lever). Without it, consecutive bids (same m-group,
// identical 221KB X-halo stream) round-robin across the 8 XCDs, so every
// XCD re-pulls the same halos through L3. swz=(bid&7)*64+(bid>>3) is
// bijective (512%8==0) and gives each XCD 4 contiguous m-groups x all 16
// co: per-XCD X footprint/c8 drops 880KB -> 110KB. Pure index remap.
// Conv is otherwise at its 2-barrier structural ceiling: R24 (-40% LDS
// reads), R25 (X-latency hidden), R26 (-18% write conflicts), R27 (2-phase
// DMA split) all flat/negative.
// Attention coords (R2/R11-verified): slab=(b<<4)+(co>>4), m=(co&15)*64+(n>>4),
//   d=n&15;  q/k rows: (slab<<14)+((co&15)<<10)+n ;  v (V^T):
//   (slab<<14)+((n&15)<<10)+((co&15)<<6)+(n>>4)
// ---------------------------------------------------------------------------
__global__ __launch_bounds__(256, 2) void convqkv_kernel(
    const unsigned short* __restrict__ xbf,
    const unsigned short* __restrict__ wFq,  // 1 tap
    const unsigned short* __restrict__ wFv,  // 9 taps
    const unsigned short* __restrict__ wFk,  // 25 taps
    const float* __restrict__ bc,            // [3][256] q,v,k
    unsigned short* __restrict__ qOut,
    unsigned short* __restrict__ vOut,
    unsigned short* __restrict__ kOut) {
  constexpr int WC = 36;            // halo cols (32 + 2*2)
  constexpr int CELLS = 12 * WC;    // 12 halo rows = 432 cells
  constexpr int LOADS = CELLS * 4;  // 1728 halo dwordx4 loads
  __shared__ unsigned short Xs[CELLS * 40];  // halo [cell][32ci pad40] 34.6KB
  __shared__ unsigned short Bs[36 * 512];    // B [tap35+1][lane64][8]  36.9KB
  const int t    = threadIdx.x;
  // XCD swizzle: bijective for 512 blocks on 8 XCDs (512 % 8 == 0).
  const int bid  = ((blockIdx.x & 7) << 6) + (blockIdx.x >> 3);
  const int cog0 = bid & 15;
  const int co0  = cog0 << 4;
  const int m0   = (bid >> 4) << 8;    // 256 positions (8 image rows)
  const int b    = m0 >> 10;
  const int n0   = m0 & 1023;
  const int r0   = n0 >> 5;
  const int wv   = t >> 6;
  const int lane = t & 63;
  const int l15  = lane & 15;
  const int quad = lane >> 4;

  floatx4 aq[4] = {}, av[4] = {}, ak[4] = {};

  for (int c8 = 0; c8 < 8; ++c8) {
    uint4 xreg[7];
#pragma unroll
    for (int rr = 0; rr < 7; ++rr) {
      const int id = rr * 256 + t;
      const int cell = id >> 2, part = id & 3;
      const int hr = cell / WC, wc = cell - hr * WC;
      const int xr = r0 + hr - 2, xc = wc - 2;
      const bool ok = (id < LOADS) && ((unsigned)xr < 32u) &&
                      ((unsigned)xc < 32u);
      const int cr = xr < 0 ? 0 : (xr > 31 ? 31 : xr);
      const int cc = xc < 0 ? 0 : (xc > 31 ? 31 : xc);
      uint4 v = *(const uint4*)&xbf[(((b * 32 + cr) * 32 + cc) << 8) +
                                    (c8 << 5) + (part << 3)];
      if (!ok) v = make_uint4(0, 0, 0, 0);
      xreg[rr] = v;
    }
    __syncthreads();
#pragma unroll
    for (int rr = 0; rr < 9; ++rr) {
      const int tap = (rr << 2) + wv;
      if (tap < 35) {
        const unsigned short* src;
        if (tap < 25) {
          src = &wFk[((((tap << 3) + c8) << 4) + cog0) * 512];
        } else if (tap < 34) {
          src = &wFv[(((((tap - 25) << 3) + c8) << 4) + cog0) * 512];
        } else {
          src = &wFq[((c8 << 4) + cog0) * 512];
        }
        __builtin_amdgcn_global_load_lds((g_u32*)(src + (lane << 3)),
                                         (l_u32*)&Bs[tap << 9], 16, 0, 0);
      }
    }
#pragma unroll
    for (int rr = 0; rr < 7; ++rr) {
      const int id = rr * 256 + t;
      if (id < LOADS)
        *(uint4*)&Xs[(id >> 2) * 40 + ((id & 3) << 3)] = xreg[rr];
    }
    __syncthreads();

#pragma unroll
    for (int kw = 0; kw < 5; ++kw) {
      // 12 distinct X frags for this kw: rows (wv*2 + 0..5), ch 0..1.
      short8 a[6][2];
#pragma unroll
      for (int ri = 0; ri < 6; ++ri) {
#pragma unroll
        for (int ch = 0; ch < 2; ++ch) {
          const unsigned short* xs =
              &Xs[(((wv << 1) + ri) * WC + (ch << 4) + l15 + kw) * 40 +
                  (quad << 3)];
          a[ri][ch] = *(const short8*)xs;
        }
      }
#pragma unroll
      for (int kh = 0; kh < 5; ++kh) {
        const int tap = kh * 5 + kw;
        const short8 kb = *(const short8*)&Bs[(tap << 9) + (lane << 3)];
#pragma unroll
        for (int rr2 = 0; rr2 < 2; ++rr2) {
#pragma unroll
          for (int ch = 0; ch < 2; ++ch) {
            const int f = (rr2 << 1) + ch;
            ak[f] = __builtin_amdgcn_mfma_f32_16x16x32_bf16(
                a[rr2 + kh][ch], kb, ak[f], 0, 0, 0);
          }
        }
        if (kh >= 1 && kh <= 3 && kw >= 1 && kw <= 3) {
          const int vt = (kh - 1) * 3 + (kw - 1);
          const short8 vb =
              *(const short8*)&Bs[((25 + vt) << 9) + (lane << 3)];
#pragma unroll
          for (int rr2 = 0; rr2 < 2; ++rr2) {
#pragma unroll
            for (int ch = 0; ch < 2; ++ch) {
              const int f = (rr2 << 1) + ch;
              av[f] = __builtin_amdgcn_mfma_f32_16x16x32_bf16(
                  a[rr2 + kh][ch], vb, av[f], 0, 0, 0);
            }
          }
        }
        if (tap == 12) {
          const short8 qb = *(const short8*)&Bs[(34 << 9) + (lane << 3)];
#pragma unroll
          for (int rr2 = 0; rr2 < 2; ++rr2) {
#pragma unroll
            for (int ch = 0; ch < 2; ++ch) {
              const int f = (rr2 << 1) + ch;
              aq[f] = __builtin_amdgcn_mfma_f32_16x16x32_bf16(
                  a[rr2 + kh][ch], qb, aq[f], 0, 0, 0);
            }
          }
        }
      }
    }
  }
#pragma unroll
  for (int rr2 = 0; rr2 < 2; ++rr2) {
#pragma unroll
    for (int ch = 0; ch < 2; ++ch) {
      const int f = (rr2 << 1) + ch;
      const int co = co0 + l15;
      const int slab = (b << 4) + (co >> 4);
      const int clo = co & 15;
      const int nb = n0 + (wv << 6) + (rr2 << 5) + (ch << 4) + (quad << 2);
      {
        const float bj = bc[co];
        floatx4 a = aq[f];
        ushort4 pk4;
        pk4.x = f2bf((a[0] + bj) * QSCALE);
        pk4.y = f2bf((a[1] + bj) * QSCALE);
        pk4.z = f2bf((a[2] + bj) * QSCALE);
        pk4.w = f2bf((a[3] + bj) * QSCALE);
        *(ushort4*)&qOut[(slab << 14) + (clo << 10) + nb] = pk4;
      }
      {
        const float bj = bc[512 + co];
        floatx4 a = ak[f];
        ushort4 pk4;
        pk4.x = f2bf(a[0] + bj); pk4.y = f2bf(a[1] + bj);
        pk4.z = f2bf(a[2] + bj); pk4.w = f2bf(a[3] + bj);
        *(ushort4*)&kOut[(slab << 14) + (clo << 10) + nb] = pk4;
      }
      {
        const float bj = bc[256 + co];
        floatx4 a = av[f];
        const int base = (slab << 14) + (clo << 6);
#pragma unroll
        for (int i = 0; i < 4; ++i) {
          const int n = nb + i;
          vOut[base + ((n & 15) << 10) + (n >> 4)] = f2bf(a[i] + bj);
        }
      }
    }
  }
}

// ---------------------------------------------------------------------------
// R29 attn: exact R3/R24-proven version (best total). K/V prefetch REVERTED
// -- isolated twice at +7us (R25 bundle, R28): launch_bounds(256,4) caps
// VGPR at 128; holding next-iter kb/vb live across the body spills.
// Swapped QK^T (mfma(kb,qa)): lane holds P[q=l31][k], 4 consecutive k per
// reg group -> packed P-store = 8 v_cvt_pk_bf16_f32 + 4 ds_write_b64/iter.
// ---------------------------------------------------------------------------
__global__ __launch_bounds__(256, 4) void attn_mfma_kernel(
    const unsigned short* __restrict__ qg,
    const unsigned short* __restrict__ kg,
    const unsigned short* __restrict__ vg,
    unsigned short* __restrict__ out2) {
  __shared__ __align__(16) unsigned short Pb[4][32][40];  // per-wave P
  const int t    = threadIdx.x;
  const int w    = t >> 6;
  const int lane = t & 63;
  const int slab = blockIdx.x >> 3;
  const int rb   = blockIdx.x & 7;
  const int b = slab >> 4;
  const int h = slab & 15;
  const int l31  = lane & 31;
  const int hl   = lane >> 5;
  const int l15  = lane & 15;
  const int quad = lane >> 4;

  const unsigned short* Kb = kg + (slab << 14);
  const unsigned short* Vb = vg + (slab << 14);

  const int row0 = (rb << 7) + (w << 5);
  const short8 qa =
      *(const short8*)&qg[(slab << 14) + ((row0 + l31) << 4) + (hl << 3)];

  const short onebf = (short)0x3F80;  // bf16 1.0
  const short8 ones = {onebf, onebf, onebf, onebf, onebf, onebf, onebf, onebf};

  floatx4 acco[2] = {}, asum[2] = {};

  for (int kc = 0; kc < 1024; kc += 32) {
    const short8 kb = *(const short8*)&Kb[((kc + l31) << 4) + (hl << 3)];
    floatx16 s = {};
    // swapped: D[m=k][n=q] -> lane holds q=l31, k = 8g + 4hl + j for s[4g+j]
    s = __builtin_amdgcn_mfma_f32_32x32x16_bf16(kb, qa, s, 0, 0, 0);
#pragma unroll
    for (int g = 0; g < 4; ++g) {
      const float e0 = __builtin_amdgcn_exp2f(s[(g << 2) + 0]);
      const float e1 = __builtin_amdgcn_exp2f(s[(g << 2) + 1]);
      const float e2 = __builtin_amdgcn_exp2f(s[(g << 2) + 2]);
      const float e3 = __builtin_amdgcn_exp2f(s[(g << 2) + 3]);
      unsigned lo, hi;
      asm("v_cvt_pk_bf16_f32 %0, %1, %2" : "=v"(lo) : "v"(e0), "v"(e1));
      asm("v_cvt_pk_bf16_f32 %0, %1, %2" : "=v"(hi) : "v"(e2), "v"(e3));
      uint2 pk; pk.x = lo; pk.y = hi;
      *(uint2*)&Pb[w][l31][(g << 3) + (hl << 2)] = pk;  // k=8g+4hl..+3
    }
    const short8 vb = *(const short8*)&Vb[(l15 << 10) + kc + (quad << 3)];
#pragma unroll
    for (int tt = 0; tt < 2; ++tt) {
      const short8 pa = *(const short8*)&Pb[w][(tt << 4) + l15][quad << 3];
      acco[tt] =
          __builtin_amdgcn_mfma_f32_16x16x32_bf16(pa, vb, acco[tt], 0, 0, 0);
      asum[tt] =
          __builtin_amdgcn_mfma_f32_16x16x32_bf16(pa, ones, asum[tt], 0, 0, 0);
    }
  }
#pragma unroll
  for (int tt = 0; tt < 2; ++tt) {
#pragma unroll
    for (int r = 0; r < 4; ++r) {
      const int nloc = (tt << 4) + (quad << 2) + r;
      const float val = acco[tt][r] / asum[tt][r];
      const int n = row0 + nloc;
      out2[(((b << 10) + n) << 8) + (h << 4) + l15] = f2bf(val);
    }
  }
}

// ---------------------------------------------------------------------------
// Final linear (R3-proven LDS-staged version, verbatim), MFMA bf16, with
// one-chunk-ahead B register prefetch.
// ---------------------------------------------------------------------------
__global__ __launch_bounds__(256) void linear_mfma_kernel(
    const unsigned short* __restrict__ inp,  // bf16 [8192][256]
    const unsigned short* __restrict__ wpF,  // fragment order
    void* __restrict__ out, const int* __restrict__ flag) {
  __shared__ unsigned short As[64 * 40];
  const int isf32 = *flag;
  const int t   = threadIdx.x;
  const int m0  = blockIdx.x << 6;
  const int co0 = blockIdx.y << 6;
  const int wv   = t >> 6;
  const int lane = t & 63;
  const int wm = (wv & 1) << 5;
  const int wn = (wv >> 1) << 5;
  const int l15  = lane & 15;
  const int quad = lane >> 4;
  const int cogb = (co0 >> 4) + (wn >> 4);
  const int rowS = t >> 2;
  const int partS = t & 3;

  floatx4 acc[2][2] = {};

  short8 cb0, cb1;
  {
    const unsigned short* wptr = &wpF[(cogb << 9) + (lane << 3)];
    cb0 = *(const short8*)wptr;
    cb1 = *(const short8*)(wptr + 512);
  }
  for (int c8 = 0; c8 < 8; ++c8) {
    const uint4 v = *(const uint4*)&inp[((m0 + rowS) << 8) + (c8 << 5) +
                                        (partS << 3)];
    short8 nb0 = {}, nb1 = {};
    if (c8 + 1 < 8) {
      const unsigned short* wptr =
          &wpF[((((c8 + 1) << 4) + cogb) << 9) + (lane << 3)];
      nb0 = *(const short8*)wptr;
      nb1 = *(const short8*)(wptr + 512);
    }
    __syncthreads();
    *(uint4*)&As[rowS * 40 + (partS << 3)] = v;
    __syncthreads();
    const unsigned short* xs = &As[(wm + l15) * 40 + (quad << 3)];
    const short8 afr0 = *(const short8*)xs;
    const short8 afr1 = *(const short8*)(xs + 16 * 40);
    acc[0][0] = __builtin_amdgcn_mfma_f32_16x16x32_bf16(afr0, cb0,
                                                        acc[0][0], 0, 0, 0);
    acc[0][1] = __builtin_amdgcn_mfma_f32_16x16x32_bf16(afr0, cb1,
                                                        acc[0][1], 0, 0, 0);
    acc[1][0] = __builtin_amdgcn_mfma_f32_16x16x32_bf16(afr1, cb0,
                                                        acc[1][0], 0, 0, 0);
    acc[1][1] = __builtin_amdgcn_mfma_f32_16x16x32_bf16(afr1, cb1,
                                                        acc[1][1], 0, 0, 0);
    cb0 = nb0; cb1 = nb1;
  }
#pragma unroll
  for (int mi = 0; mi < 2; ++mi) {
#pragma unroll
    for (int ni = 0; ni < 2; ++ni) {
      const int co = co0 + wn + (ni << 4) + l15;
      const int mb = m0 + wm + (mi << 4) + (quad << 2);
      floatx4 a = acc[mi][ni];
      if (!isf32) {
        unsigned short* o16 = (unsigned short*)out;
#pragma unroll
        for (int r = 0; r < 4; ++r) o16[(mb + r) * 256 + co] = f2bf(a[r]);
      } else {
        float* o32 = (float*)out;
#pragma unroll
        for (int r = 0; r < 4; ++r) o32[(mb + r) * 256 + co] = a[r];
      }
    }
  }
}

// ---------------------------------------------------------------------------
extern "C" void kernel_launch(void* const* d_in, const int* in_sizes, int n_in,
                              void* d_out, int out_size, void* d_ws,
                              size_t ws_size, hipStream_t stream) {
  const void* x  = d_in[0];
  const void* w3 = d_in[1];
  const void* b3 = d_in[2];
  const void* w5 = d_in[3];
  const void* b5 = d_in[4];
  const void* w7 = d_in[5];
  const void* b7 = d_in[6];
  const void* wp = d_in[7];

  char* p = (char*)d_ws;
  int* flag = (int*)p;                       p += 256;
  unsigned short* xbf = (unsigned short*)p;  p += 4u * 1024 * 1024;
  unsigned short* wF3 = (unsigned short*)p;  p += 131072;
  unsigned short* wF5 = (unsigned short*)p;  p += 1179648;
  unsigned short* wF7 = (unsigned short*)p;  p += 3276800;
  unsigned short* wpF = (unsigned short*)p;  p += 131072;
  float* bc = (float*)p;                     p += 4096;     // [3][256]
  unsigned short* qc  = (unsigned short*)p;  p += 4194304;  // bf16 QK rows
  unsigned short* kT  = (unsigned short*)p;  p += 4194304;  // bf16 QK rows
  unsigned short* vT  = (unsigned short*)p;  p += 4194304;  // bf16 V^T
  unsigned short* o2b = (unsigned short*)p;  p += 4194304;  // bf16 [8192][256]

  prep_kernel<<<1025, 256, 0, stream>>>(x, w3, b3, w5, b5, w7, b7, wp, xbf,
                                        wF3, wF5, wF7, wpF, bc, flag);

  convqkv_kernel<<<512, 256, 0, stream>>>(xbf, wF3, wF5, wF7, bc, qc, vT, kT);

  attn_mfma_kernel<<<1024, 256, 0, stream>>>(qc, kT, vT, o2b);

  dim3 lg(128, 4);
  linear_mfma_kernel<<<lg, 256, 0, stream>>>(o2b, wpF, d_out, flag);
}